// Round 7
// baseline (71.984 us; speedup 1.0000x reference)
//
#include <hip/hip_runtime.h>
#include <hip/hip_bf16.h>
#include <cstdint>

#define NROWS 8192
#define NPER  4096
#define DIM   512
#define TEMP_INV 10.0f
#define NRB   32        // 8192 / 256 row-blocks (256-row stripes)
#define NBLK  1056      // sum_{bi<32} (64 - 2*bi) rect tiles covering upper tri
#define PAIR_OFF 32

typedef __bf16 bf16x8 __attribute__((ext_vector_type(8)));
typedef float  f32x4  __attribute__((ext_vector_type(4)));

__device__ __forceinline__ unsigned short f2bf(float f) {
  unsigned int u = __builtin_bit_cast(unsigned int, f);
  u += 0x7FFFu + ((u >> 16) & 1u);
  return (unsigned short)(u >> 16);
}

// ---------------------------------------------------------------------------
// Kernel 1: L2-normalize rows of [view0; view1] -> z (bf16, [8192][512]).
// Also zeroes rowsum and out.
// ---------------------------------------------------------------------------
__global__ __launch_bounds__(256) void k_normalize(const float* __restrict__ v0,
                                                   const float* __restrict__ v1,
                                                   unsigned short* __restrict__ z,
                                                   float* __restrict__ rowsum,
                                                   float* __restrict__ out) {
  if (blockIdx.x < 32) rowsum[blockIdx.x * 256 + threadIdx.x] = 0.f;
  if (blockIdx.x == 0 && threadIdx.x == 0) out[0] = 0.f;
  const int wid  = (blockIdx.x * 256 + threadIdx.x) >> 6;  // row
  const int lane = threadIdx.x & 63;
  if (wid >= NROWS) return;
  const float* src = (wid < NPER) ? (v0 + (size_t)wid * DIM)
                                  : (v1 + (size_t)(wid - NPER) * DIM);
  float4 a = *(const float4*)(src + lane * 8);
  float4 b = *(const float4*)(src + lane * 8 + 4);
  float ss = a.x*a.x + a.y*a.y + a.z*a.z + a.w*a.w
           + b.x*b.x + b.y*b.y + b.z*b.z + b.w*b.w;
  #pragma unroll
  for (int m = 1; m < 64; m <<= 1) ss += __shfl_xor(ss, m);
  float inv = 1.0f / fmaxf(sqrtf(ss), 1e-12f);
  union { unsigned short us[8]; uint4 v; } p;
  p.us[0] = f2bf(a.x * inv); p.us[1] = f2bf(a.y * inv);
  p.us[2] = f2bf(a.z * inv); p.us[3] = f2bf(a.w * inv);
  p.us[4] = f2bf(b.x * inv); p.us[5] = f2bf(b.y * inv);
  p.us[6] = f2bf(b.z * inv); p.us[7] = f2bf(b.w * inv);
  *(uint4*)(z + (size_t)wid * DIM + lane * 8) = p.v;
}

// ---------------------------------------------------------------------------
// Kernel 2: symmetric fused G = z z^T, 256(row) x 128(col) rectangular tiles
// covering the strict upper triangle. 8 waves (4x2), per-wave 64x64
// (acc[4][4] = 64 AGPR; 64 VGPR -> 128 regs/wave -> 16 waves/CU), BK=64
// SINGLE-buffered (LDS 48 KB -> 2 blocks/CU by VGPR, i.e. 16 waves/CU vs
// R4's 12) and staged traffic x0.74 (1056 x 384 KB = 405 MB vs 546 MB).
// Per-wave inner loop is byte-identical to the R4-verified 64x64 kernel.
// Tiling: row-stripe bi (256 rows), col-blocks j in [2*bi, 64) (128 cols).
// Coverage: r<=c => (c>>7) >= 2*(r>>8), each (r,c) in exactly one tile.
// Epilogue masks STRICT upper (grow < gcol): sub-diagonal duplicates in the
// two diagonal-straddling tiles are excluded (their mirrors are the upper
// elements); no diag special case needed. e added to rowsum[grow] (racc)
// and rowsum[gcol] (cacc) -> rowsum[i] = sum_{j != i} exp(g_ij/T).
// Positive-pair diagonal (gcol = grow + 4096) lives in tiles dt in {32,33}.
// T1 chunked XCD swizzle (1056 % 8 == 0). T2 swizzle as verified in R4.
// ---------------------------------------------------------------------------
__global__ __launch_bounds__(512, 4) void k_gemm_sym(const unsigned short* __restrict__ z,
                                                     float* __restrict__ rowsum,
                                                     float* __restrict__ s) {
  __shared__ __align__(16) unsigned short As[256 * 64];   // 32 KB
  __shared__ __align__(16) unsigned short Bs[128 * 64];   // 16 KB

  const int tid  = threadIdx.x;
  const int lane = tid & 63;
  const int w    = tid >> 6;      // 0..7
  const int wr   = w >> 1;        // 0..3 (row quarter, 64 rows each)
  const int wc   = w & 1;         // 0..1 (col half, 64 cols each)

  // T1: bijective chunked XCD swizzle (1056 % 8 == 0)
  const int orig = blockIdx.x;
  const int t = (orig & 7) * (NBLK / 8) + (orig >> 3);
  // decode: start(bi) = bi*(65-bi); bi = largest with start(bi) <= t
  int bi = (int)((65.0f - sqrtf((float)(4225 - 4 * t))) * 0.5f);
  while ((bi + 1) * (65 - (bi + 1)) <= t) ++bi;
  while (bi * (65 - bi) > t) --bi;
  const int dt    = t - bi * (65 - bi);      // 0 .. 63-2*bi
  const int jcb   = 2 * bi + dt;             // col-block (128 wide)
  const int brow  = bi * 256;
  const int bcol  = jcb * 128;
  const bool pair = (dt == 32) || (dt == 33);  // holds +NPER diagonal

  f32x4 acc[4][4];
  const f32x4 zero = {0.f, 0.f, 0.f, 0.f};
  #pragma unroll
  for (int m = 0; m < 4; ++m)
    #pragma unroll
    for (int n = 0; n < 4; ++n) acc[m][n] = zero;

  // Stage one BK=64 K-slab: A 256x64 (32 KB, 4 loads/thread) + B 128x64
  // (16 KB, 2 loads/thread). LDS dest linear; global source pre-swizzled
  // (rule #21): phys_byte = logical_byte ^ ((row & 7) << 4).
  const int srow = (lane >> 3);                  // 0..7 row within chunk
  const int skof = 8 * ((lane & 7) ^ srow);      // pre-swizzled k-offset (elems)
  auto stage = [&](int k0) {
    #pragma unroll
    for (int i = 0; i < 4; ++i) {                // A: 32 chunks of 8 rows
      const int c = w * 4 + i;
      const int row_in = c * 8 + srow;
      const unsigned short* ga = z + (size_t)(brow + row_in) * DIM + k0 + skof;
      __builtin_amdgcn_global_load_lds(
          (const __attribute__((address_space(1))) void*)ga,
          (__attribute__((address_space(3))) void*)(&As[c * 512]), 16, 0, 0);
    }
    #pragma unroll
    for (int i = 0; i < 2; ++i) {                // B: 16 chunks of 8 rows
      const int c = w * 2 + i;
      const int row_in = c * 8 + srow;
      const unsigned short* gb = z + (size_t)(bcol + row_in) * DIM + k0 + skof;
      __builtin_amdgcn_global_load_lds(
          (const __attribute__((address_space(1))) void*)gb,
          (__attribute__((address_space(3))) void*)(&Bs[c * 512]), 16, 0, 0);
    }
  };

  const int r0 = lane & 15;
  const int g  = lane >> 4;
  const int sw = (r0 & 7) << 4;                  // swizzle XOR (bits 4-6)

  for (int kt = 0; kt < 8; ++kt) {
    stage(kt * 64);
    asm volatile("s_waitcnt vmcnt(0)" ::: "memory");
    __builtin_amdgcn_s_barrier();

    const char* Ab = (const char*)&As[0];
    const char* Bb = (const char*)&Bs[0];
    #pragma unroll
    for (int kk = 0; kk < 2; ++kk) {
      const int kb = kk * 64 + g * 16;           // k byte-offset within row
      bf16x8 bfrag[4];
      #pragma unroll
      for (int n = 0; n < 4; ++n)
        bfrag[n] = *(const bf16x8*)(Bb + (((wc * 64 + n * 16 + r0) * 128 + kb) ^ sw));
      #pragma unroll
      for (int m = 0; m < 4; ++m) {
        bf16x8 afrag = *(const bf16x8*)(Ab + (((wr * 64 + m * 16 + r0) * 128 + kb) ^ sw));
        #pragma unroll
        for (int n = 0; n < 4; ++n)
          acc[m][n] = __builtin_amdgcn_mfma_f32_16x16x32_bf16(afrag, bfrag[n],
                                                              acc[m][n], 0, 0, 0);
      }
    }
    asm volatile("s_waitcnt lgkmcnt(0)" ::: "memory");
    __builtin_amdgcn_sched_barrier(0);
    __builtin_amdgcn_s_barrier();
  }

  // ---- epilogue: exp(10*g); strict-upper mask; row + col partial sums ----
  float (*racc)[256] = (float (*)[256])As;        // [2][256]  (col-half wc)
  float (*cacc)[128] = (float (*)[128])(As + 1024); // [4][128] (row-qtr wr)

  float cs[4] = {0.f, 0.f, 0.f, 0.f};
  const int grow0 = brow + wr * 64;
  const int gcol0 = bcol + wc * 64;
  #pragma unroll
  for (int m = 0; m < 4; ++m) {
    #pragma unroll
    for (int j = 0; j < 4; ++j) {
      const int grow = grow0 + m * 16 + g * 4 + j;
      float v = 0.f;
      #pragma unroll
      for (int n = 0; n < 4; ++n) {
        const int gcol = gcol0 + n * 16 + r0;
        const float raw = acc[m][n][j];
        const float e = __expf(raw * TEMP_INV);
        if (grow < gcol) { v += e; cs[n] += e; }    // strict upper only
        if (pair && (grow + NPER == gcol)) {        // positive-pair raw dot
          s[grow] = raw;
          s[gcol] = raw;
        }
      }
      v += __shfl_xor(v, 1);
      v += __shfl_xor(v, 2);
      v += __shfl_xor(v, 4);
      v += __shfl_xor(v, 8);
      if (r0 == 0) racc[wc][wr * 64 + m * 16 + g * 4 + j] = v;
    }
  }
  #pragma unroll
  for (int n = 0; n < 4; ++n) {
    float v = cs[n];
    v += __shfl_xor(v, 16);
    v += __shfl_xor(v, 32);
    if (lane < 16) cacc[wr][wc * 64 + n * 16 + lane] = v;
  }
  __syncthreads();
  if (tid < 256) {
    atomicAdd(&rowsum[brow + tid], racc[0][tid] + racc[1][tid]);
  } else if (tid < 384) {
    const int i = tid - 256;
    atomicAdd(&rowsum[bcol + i],
              cacc[0][i] + cacc[1][i] + cacc[2][i] + cacc[3][i]);
  }
}

// ---------------------------------------------------------------------------
// Kernel 3: loss = mean_i( log(denom_i) - s_i/T ), 32 blocks + atomicAdd.
// ---------------------------------------------------------------------------
__global__ __launch_bounds__(256) void k_loss(const float* __restrict__ rowsum,
                                              const float* __restrict__ s,
                                              float* __restrict__ out) {
  __shared__ float red[4];
  const int i = blockIdx.x * 256 + threadIdx.x;
  float v = logf(rowsum[i]) - s[i] * TEMP_INV;
  #pragma unroll
  for (int m = 1; m < 64; m <<= 1) v += __shfl_xor(v, m);
  const int w = threadIdx.x >> 6;
  if ((threadIdx.x & 63) == 0) red[w] = v;
  __syncthreads();
  if (threadIdx.x == 0)
    atomicAdd(out, (red[0] + red[1] + red[2] + red[3]) * (1.0f / (float)NROWS));
}

extern "C" void kernel_launch(void* const* d_in, const int* in_sizes, int n_in,
                              void* d_out, int out_size, void* d_ws, size_t ws_size,
                              hipStream_t stream) {
  const float* v0 = (const float*)d_in[0];
  const float* v1 = (const float*)d_in[1];
  float* out = (float*)d_out;

  unsigned short* z = (unsigned short*)d_ws;                    // 8192*512*2 B
  float* rowsum = (float*)((char*)d_ws + (size_t)NROWS * DIM * 2);
  float* s      = rowsum + NROWS;

  k_normalize<<<NROWS / 4, 256, 0, stream>>>(v0, v1, z, rowsum, out);
  k_gemm_sym<<<NBLK, 512, 0, stream>>>(z, rowsum, s);
  k_loss<<<NROWS / 256, 256, 0, stream>>>(rowsum, s, out);
}

// Round 8
// 63.905 us; speedup vs baseline: 1.1264x; 1.1264x over previous
//
#include <hip/hip_runtime.h>
#include <hip/hip_bf16.h>
#include <cstdint>

#define NROWS 8192
#define NPER  4096
#define DIM   512
#define TEMP_INV 10.0f
#define NB    64        // 8192 / 128 row-blocks
#define NBLK  2080      // NB*(NB+1)/2 upper-tri 128x128 tiles
#define PAIR_OFF 32     // NPER / 128

typedef __bf16 bf16x8 __attribute__((ext_vector_type(8)));
typedef float  f32x4  __attribute__((ext_vector_type(4)));

__device__ __forceinline__ unsigned short f2bf(float f) {
  unsigned int u = __builtin_bit_cast(unsigned int, f);
  u += 0x7FFFu + ((u >> 16) & 1u);
  return (unsigned short)(u >> 16);
}

// ---------------------------------------------------------------------------
// Kernel 1: L2-normalize rows of [view0; view1] -> z (bf16, [8192][512]).
// Also zeroes rowsum and out (replaces memset + enables atomic k_loss).
// ---------------------------------------------------------------------------
__global__ __launch_bounds__(256) void k_normalize(const float* __restrict__ v0,
                                                   const float* __restrict__ v1,
                                                   unsigned short* __restrict__ z,
                                                   float* __restrict__ rowsum,
                                                   float* __restrict__ out) {
  if (blockIdx.x < 32) rowsum[blockIdx.x * 256 + threadIdx.x] = 0.f;
  if (blockIdx.x == 0 && threadIdx.x == 0) out[0] = 0.f;
  const int wid  = (blockIdx.x * 256 + threadIdx.x) >> 6;  // row
  const int lane = threadIdx.x & 63;
  if (wid >= NROWS) return;
  const float* src = (wid < NPER) ? (v0 + (size_t)wid * DIM)
                                  : (v1 + (size_t)(wid - NPER) * DIM);
  float4 a = *(const float4*)(src + lane * 8);
  float4 b = *(const float4*)(src + lane * 8 + 4);
  float ss = a.x*a.x + a.y*a.y + a.z*a.z + a.w*a.w
           + b.x*b.x + b.y*b.y + b.z*b.z + b.w*b.w;
  #pragma unroll
  for (int m = 1; m < 64; m <<= 1) ss += __shfl_xor(ss, m);
  float inv = 1.0f / fmaxf(sqrtf(ss), 1e-12f);
  union { unsigned short us[8]; uint4 v; } p;
  p.us[0] = f2bf(a.x * inv); p.us[1] = f2bf(a.y * inv);
  p.us[2] = f2bf(a.z * inv); p.us[3] = f2bf(a.w * inv);
  p.us[4] = f2bf(b.x * inv); p.us[5] = f2bf(b.y * inv);
  p.us[6] = f2bf(b.z * inv); p.us[7] = f2bf(b.w * inv);
  *(uint4*)(z + (size_t)wid * DIM + lane * 8) = p.v;
}

// ---------------------------------------------------------------------------
// Kernel 2: symmetric fused G = z z^T, 128x128 upper-triangular tiles,
// 4 waves (2x2), per-wave 64x64 (acc[4][4]), BK=64 SINGLE-buffered.
// Structure is the R4-verified optimum (3 independent blocks/CU = the
// register-file ceiling at 64 VGPR + 64 AGPR; all deeper-pipeline and
// bigger-tile variants measured worse).
// NEW (R8): super-tile locality mapping. The 64x64 block-triangle is grouped
// into 8x8 super-tiles (36 supers: 8 diagonal with 36 tiles, 28 off-diagonal
// with 64; total 2080). Tiles are enumerated super-by-super and dealt to
// XCDs in contiguous 260-tile chunks (T1, 2080%8==0). An XCD's ~96
// concurrent tiles then lie within 1-2 supers -> instantaneous working set
// = 8 A-panels + 8 B-panels = 2 MB, resident in the 4 MB per-XCD L2, each
// panel reused 8x by concurrent blocks. Staging becomes L2-hit (~200 cyc)
// instead of L3 round trips (~600-900 cyc) -> shorter vmcnt(0) drains.
// (Old order: bj-fast along a stripe = ~96 distinct concurrent B panels
// = 12 MB >> L2; FETCH_SIZE 53 MB = 6.6x z confirmed L2 thrash.)
// T2 XOR-swizzled LDS (linear dest + pre-swizzled global source, rule #21).
// Positive-pair dots harvested from raw acc of tiles with bj-bi == 32.
// Epilogue smem arrays aliased into As (keeps LDS at exactly 32 KB).
// ---------------------------------------------------------------------------
__global__ __launch_bounds__(256, 3) void k_gemm_sym(const unsigned short* __restrict__ z,
                                                     float* __restrict__ rowsum,
                                                     float* __restrict__ s) {
  __shared__ __align__(16) unsigned short As[128 * 64];   // 16 KB
  __shared__ __align__(16) unsigned short Bs[128 * 64];   // 16 KB

  const int tid  = threadIdx.x;
  const int lane = tid & 63;
  const int w    = tid >> 6;      // 0..3
  const int wr   = w >> 1;        // 0..1 (row half)
  const int wc   = w & 1;        // 0..1 (col half)

  // T1 chunking: XCD x processes enumeration indices [x*260, (x+1)*260).
  const int orig = blockIdx.x;
  const int t = (orig & 7) * (NBLK / 8) + (orig >> 3);

  // ---- super-tile decode ----
  // super-row a (a=si): 1 diag super (36 tiles) + (7-a) off supers (64 each)
  // rowstart(a) = 484a - 32a(a-1)
  int a = 0;
  while (a < 7 && 484 * (a + 1) - 32 * (a + 1) * a <= t) ++a;
  int l = t - (484 * a - 32 * a * (a - 1));
  int ri, rj, sj;
  if (l < 36) {                      // diagonal super (si == sj == a)
    sj = a;
    ri = 0;
    while (l >= 8 - ri) { l -= 8 - ri; ++ri; }
    rj = ri + l;
  } else {                           // off-diagonal supers, 64 tiles each
    l -= 36;
    sj = a + 1 + (l >> 6);
    const int ll = l & 63;
    ri = ll >> 3; rj = ll & 7;
  }
  const int bi = a * 8 + ri;
  const int bj = sj * 8 + rj;
  const int brow = bi * 128;
  const int bcol = bj * 128;
  const bool diag = (bi == bj);
  const bool pair = (bj - bi == PAIR_OFF);  // contains positive-pair diagonal

  f32x4 acc[4][4];
  const f32x4 zero = {0.f, 0.f, 0.f, 0.f};
  #pragma unroll
  for (int m = 0; m < 4; ++m)
    #pragma unroll
    for (int n = 0; n < 4; ++n) acc[m][n] = zero;

  // stage one BK=64 K-slab (A and B tiles, 16 KB each). 8 global_load_lds
  // per thread. LDS dest linear; global source pre-swizzled (rule #21):
  // phys_byte = logical_byte ^ ((row & 7) << 4).
  const int srow = (lane >> 3);                  // 0..7 row within chunk
  const int skof = 8 * ((lane & 7) ^ srow);      // pre-swizzled k-offset (elems)
  auto stage = [&](int k0) {
    #pragma unroll
    for (int i = 0; i < 4; ++i) {
      const int c = w * 4 + i;                   // chunk 0..15 (8 rows each)
      const int row_in = c * 8 + srow;
      const unsigned short* ga = z + (size_t)(brow + row_in) * DIM + k0 + skof;
      const unsigned short* gb = z + (size_t)(bcol + row_in) * DIM + k0 + skof;
      __builtin_amdgcn_global_load_lds(
          (const __attribute__((address_space(1))) void*)ga,
          (__attribute__((address_space(3))) void*)(&As[c * 512]), 16, 0, 0);
      __builtin_amdgcn_global_load_lds(
          (const __attribute__((address_space(1))) void*)gb,
          (__attribute__((address_space(3))) void*)(&Bs[c * 512]), 16, 0, 0);
    }
  };

  const int r0 = lane & 15;
  const int g  = lane >> 4;
  const int sw = (r0 & 7) << 4;                  // swizzle XOR (bits 4-6)

  for (int kt = 0; kt < 8; ++kt) {
    stage(kt * 64);
    // single buffer: own loads drained, then all waves' loads visible.
    asm volatile("s_waitcnt vmcnt(0)" ::: "memory");
    __builtin_amdgcn_s_barrier();

    const char* Ab = (const char*)&As[0];
    const char* Bb = (const char*)&Bs[0];
    #pragma unroll
    for (int kk = 0; kk < 2; ++kk) {
      const int kb = kk * 64 + g * 16;           // k byte-offset within row
      bf16x8 bfrag[4];
      #pragma unroll
      for (int n = 0; n < 4; ++n)
        bfrag[n] = *(const bf16x8*)(Bb + (((wc * 64 + n * 16 + r0) * 128 + kb) ^ sw));
      #pragma unroll
      for (int m = 0; m < 4; ++m) {
        bf16x8 afrag = *(const bf16x8*)(Ab + (((wr * 64 + m * 16 + r0) * 128 + kb) ^ sw));
        #pragma unroll
        for (int n = 0; n < 4; ++n)
          acc[m][n] = __builtin_amdgcn_mfma_f32_16x16x32_bf16(afrag, bfrag[n],
                                                              acc[m][n], 0, 0, 0);
      }
    }
    // all LDS reads done in this wave, sync all waves -> safe to overwrite.
    asm volatile("s_waitcnt lgkmcnt(0)" ::: "memory");
    __builtin_amdgcn_sched_barrier(0);
    __builtin_amdgcn_s_barrier();
  }

  // ---- epilogue: exp(10*g); row sums + col sums (symmetry); pair dots ----
  // smem reduction arrays aliased into As (all LDS reads drained above).
  float (*racc)[128] = (float (*)[128])As;        // [2][128]
  float (*cacc)[128] = ((float (*)[128])As) + 2;  // [2][128]

  float cs[4] = {0.f, 0.f, 0.f, 0.f};
  const int grow0 = brow + wr * 64;
  const int gcol0 = bcol + wc * 64;
  #pragma unroll
  for (int m = 0; m < 4; ++m) {
    #pragma unroll
    for (int j = 0; j < 4; ++j) {
      const int grow = grow0 + m * 16 + g * 4 + j;
      float v = 0.f;
      #pragma unroll
      for (int n = 0; n < 4; ++n) {
        const int gcol = gcol0 + n * 16 + r0;
        const float raw = acc[m][n][j];
        const float e = __expf(raw * TEMP_INV);
        if (grow != gcol) { v += e; cs[n] += e; }   // skip self-similarity
        if (pair && (grow + NPER == gcol)) {        // positive-pair raw dot
          s[grow] = raw;                            // dot(z_i, z_{i+NPER})
          s[gcol] = raw;                            // symmetric partner
        }
      }
      v += __shfl_xor(v, 1);
      v += __shfl_xor(v, 2);
      v += __shfl_xor(v, 4);
      v += __shfl_xor(v, 8);
      if (r0 == 0) racc[wc][wr * 64 + m * 16 + g * 4 + j] = v;
    }
  }
  #pragma unroll
  for (int n = 0; n < 4; ++n) {
    float v = cs[n];
    v += __shfl_xor(v, 16);
    v += __shfl_xor(v, 32);
    if (lane < 16) cacc[wr][wc * 64 + n * 16 + lane] = v;
  }
  __syncthreads();
  if (tid < 128) {
    atomicAdd(&rowsum[brow + tid], racc[0][tid] + racc[1][tid]);
  } else if (!diag) {
    const int i = tid - 128;
    atomicAdd(&rowsum[bcol + i], cacc[0][i] + cacc[1][i]);
  }
}

// ---------------------------------------------------------------------------
// Kernel 3: loss = mean_i( log(denom_i) - s_i/T ), 32 blocks + atomicAdd
// (out zeroed in k_normalize; stream order guarantees visibility).
// ---------------------------------------------------------------------------
__global__ __launch_bounds__(256) void k_loss(const float* __restrict__ rowsum,
                                              const float* __restrict__ s,
                                              float* __restrict__ out) {
  __shared__ float red[4];
  const int i = blockIdx.x * 256 + threadIdx.x;
  float v = logf(rowsum[i]) - s[i] * TEMP_INV;
  #pragma unroll
  for (int m = 1; m < 64; m <<= 1) v += __shfl_xor(v, m);
  const int w = threadIdx.x >> 6;
  if ((threadIdx.x & 63) == 0) red[w] = v;
  __syncthreads();
  if (threadIdx.x == 0)
    atomicAdd(out, (red[0] + red[1] + red[2] + red[3]) * (1.0f / (float)NROWS));
}

extern "C" void kernel_launch(void* const* d_in, const int* in_sizes, int n_in,
                              void* d_out, int out_size, void* d_ws, size_t ws_size,
                              hipStream_t stream) {
  const float* v0 = (const float*)d_in[0];
  const float* v1 = (const float*)d_in[1];
  float* out = (float*)d_out;

  unsigned short* z = (unsigned short*)d_ws;                    // 8192*512*2 B
  float* rowsum = (float*)((char*)d_ws + (size_t)NROWS * DIM * 2);
  float* s      = rowsum + NROWS;

  k_normalize<<<NROWS / 4, 256, 0, stream>>>(v0, v1, z, rowsum, out);
  k_gemm_sym<<<NBLK, 256, 0, stream>>>(z, rowsum, s);
  k_loss<<<NROWS / 256, 256, 0, stream>>>(rowsum, s, out);
}

// Round 9
// 51.141 us; speedup vs baseline: 1.4076x; 1.2496x over previous
//
#include <hip/hip_runtime.h>
#include <hip/hip_bf16.h>
#include <cstdint>

#define NROWS 8192
#define NPER  4096
#define DIM   512
#define TEMP_INV 10.0f
#define FP8_SCALE 16.0f          // z scaled by 16 before e4m3 quantization
#define DOT_UNSCALE (1.0f / 256.0f)  // undo FP8_SCALE^2 on dot products
#define NB    64        // 8192 / 128 row-blocks
#define NBLK  2080      // NB*(NB+1)/2 upper-tri 128x128 tiles
#define PAIR_OFF 32     // NPER / 128

typedef float f32x4 __attribute__((ext_vector_type(4)));

// ---------------------------------------------------------------------------
// Kernel 1: L2-normalize rows of [view0; view1] -> z (fp8 e4m3, [8192][512]),
// scaled by FP8_SCALE (moves typical |z|~0.04 out of the subnormal zone;
// e4m3 max 448 >> 16). Also zeroes rowsum and out.
// ---------------------------------------------------------------------------
__global__ __launch_bounds__(256) void k_normalize(const float* __restrict__ v0,
                                                   const float* __restrict__ v1,
                                                   unsigned char* __restrict__ z,
                                                   float* __restrict__ rowsum,
                                                   float* __restrict__ out) {
  if (blockIdx.x < 32) rowsum[blockIdx.x * 256 + threadIdx.x] = 0.f;
  if (blockIdx.x == 0 && threadIdx.x == 0) out[0] = 0.f;
  const int wid  = (blockIdx.x * 256 + threadIdx.x) >> 6;  // row
  const int lane = threadIdx.x & 63;
  if (wid >= NROWS) return;
  const float* src = (wid < NPER) ? (v0 + (size_t)wid * DIM)
                                  : (v1 + (size_t)(wid - NPER) * DIM);
  float4 a = *(const float4*)(src + lane * 8);
  float4 b = *(const float4*)(src + lane * 8 + 4);
  float ss = a.x*a.x + a.y*a.y + a.z*a.z + a.w*a.w
           + b.x*b.x + b.y*b.y + b.z*b.z + b.w*b.w;
  #pragma unroll
  for (int m = 1; m < 64; m <<= 1) ss += __shfl_xor(ss, m);
  float inv = FP8_SCALE / fmaxf(sqrtf(ss), 1e-12f);
  // pack 8 fp8 e4m3 (hardware v_cvt_pk_fp8_f32, RNE, OCP format on gfx950)
  int w0 = __builtin_amdgcn_cvt_pk_fp8_f32(a.x * inv, a.y * inv, 0, false);
  w0     = __builtin_amdgcn_cvt_pk_fp8_f32(a.z * inv, a.w * inv, w0, true);
  int w1 = __builtin_amdgcn_cvt_pk_fp8_f32(b.x * inv, b.y * inv, 0, false);
  w1     = __builtin_amdgcn_cvt_pk_fp8_f32(b.z * inv, b.w * inv, w1, true);
  uint2 p; p.x = (unsigned)w0; p.y = (unsigned)w1;
  *(uint2*)(z + (size_t)wid * DIM + lane * 8) = p;
}

// ---------------------------------------------------------------------------
// Kernel 2: symmetric fused G = z z^T in FP8 e4m3 (mfma_f32_16x16x32_fp8_fp8,
// bf16-rate, half the bytes). 128x128 upper-tri tiles, 4 waves (2x2),
// per-wave 64x64 (acc[4][4] = 64 AGPR), BK=128 SINGLE-buffered: A+B tiles
// = 2 x 16 KB = 32 KB LDS -> 3 blocks/CU (the R4-verified residency optimum)
// and only 4 K-iterations (halves per-iter fixed overhead).
// R8 model: time ~ bytes staged per resident block (~7 B/cyc/block).
// fp8 halves staged traffic 532->266 MB; z (4 MB) is L2-resident per XCD.
// Fragment-layout safety: A and B are read with the IDENTICAL per-lane
// k-mapping, so any within-k32 lane permutation cancels in the dot product.
// Swizzle (128-B rows, 16-B units): phys16slot = log16slot ^ (row & 7);
// staging pre-swizzles the global source (rule #21), 8-B ds_reads apply the
// same XOR on bits 4-6 (<=2-way banks). R8 super-tile locality map kept.
// Positive-pair dots harvested from raw acc of tiles with bj-bi == 32.
// ---------------------------------------------------------------------------
__global__ __launch_bounds__(256, 3) void k_gemm_sym(const unsigned char* __restrict__ z,
                                                     float* __restrict__ rowsum,
                                                     float* __restrict__ s) {
  __shared__ __align__(16) unsigned char As[128 * 128];   // 16 KB
  __shared__ __align__(16) unsigned char Bs[128 * 128];   // 16 KB

  const int tid  = threadIdx.x;
  const int lane = tid & 63;
  const int w    = tid >> 6;      // 0..3
  const int wr   = w >> 1;        // 0..1 (row half)
  const int wc   = w & 1;         // 0..1 (col half)

  // T1 chunking: XCD x processes enumeration indices [x*260, (x+1)*260).
  const int orig = blockIdx.x;
  const int t = (orig & 7) * (NBLK / 8) + (orig >> 3);

  // ---- super-tile decode (R8) ----
  int a = 0;
  while (a < 7 && 484 * (a + 1) - 32 * (a + 1) * a <= t) ++a;
  int l = t - (484 * a - 32 * a * (a - 1));
  int ri, rj, sj;
  if (l < 36) {                      // diagonal super (si == sj == a)
    sj = a;
    ri = 0;
    while (l >= 8 - ri) { l -= 8 - ri; ++ri; }
    rj = ri + l;
  } else {                           // off-diagonal supers, 64 tiles each
    l -= 36;
    sj = a + 1 + (l >> 6);
    const int ll = l & 63;
    ri = ll >> 3; rj = ll & 7;
  }
  const int bi = a * 8 + ri;
  const int bj = sj * 8 + rj;
  const int brow = bi * 128;
  const int bcol = bj * 128;
  const bool diag = (bi == bj);
  const bool pair = (bj - bi == PAIR_OFF);  // contains positive-pair diagonal

  f32x4 acc[4][4];
  const f32x4 zero = {0.f, 0.f, 0.f, 0.f};
  #pragma unroll
  for (int m = 0; m < 4; ++m)
    #pragma unroll
    for (int n = 0; n < 4; ++n) acc[m][n] = zero;

  // stage one BK=128 K-slab (A and B tiles, 16 KB each). 8 global_load_lds
  // per thread (4 A + 4 B). Chunk = 8 rows x 128 B = 1 KB (one wave-load).
  // LDS dest linear; global source pre-swizzled: 16B-slot ^= (row & 7).
  const int srow = (lane >> 3);                  // 0..7 row within chunk
  const int skof = 16 * ((lane & 7) ^ srow);     // pre-swizzled k-offset (bytes)
  auto stage = [&](int k0) {
    #pragma unroll
    for (int i = 0; i < 4; ++i) {
      const int c = w * 4 + i;                   // chunk 0..15 (8 rows each)
      const int row_in = c * 8 + srow;
      const unsigned char* ga = z + (size_t)(brow + row_in) * DIM + k0 + skof;
      const unsigned char* gb = z + (size_t)(bcol + row_in) * DIM + k0 + skof;
      __builtin_amdgcn_global_load_lds(
          (const __attribute__((address_space(1))) void*)ga,
          (__attribute__((address_space(3))) void*)(&As[c * 1024]), 16, 0, 0);
      __builtin_amdgcn_global_load_lds(
          (const __attribute__((address_space(1))) void*)gb,
          (__attribute__((address_space(3))) void*)(&Bs[c * 1024]), 16, 0, 0);
    }
  };

  const int r0 = lane & 15;
  const int g  = lane >> 4;
  // per-kk swizzled column offset within a 128-B row for this lane's 8-B frag:
  // logical byte = kk*32 + g*8; 16B-slot = kk*2 + (g>>1); phys = (slot ^
  // (r0&7))<<4 | (g&1)<<3.
  int colk[4];
  #pragma unroll
  for (int kk = 0; kk < 4; ++kk)
    colk[kk] = (((kk * 2 + (g >> 1)) ^ (r0 & 7)) << 4) + ((g & 1) << 3);

  for (int kt = 0; kt < 4; ++kt) {
    stage(kt * 128);
    // single buffer: own loads drained, then all waves' loads visible.
    asm volatile("s_waitcnt vmcnt(0)" ::: "memory");
    __builtin_amdgcn_s_barrier();

    const char* Ab = (const char*)&As[0] + (size_t)(wr * 64 + r0) * 128;
    const char* Bb = (const char*)&Bs[0] + (size_t)(wc * 64 + r0) * 128;
    #pragma unroll
    for (int kk = 0; kk < 4; ++kk) {
      const int cb = colk[kk];
      long bfrag[4];
      #pragma unroll
      for (int n = 0; n < 4; ++n)
        bfrag[n] = *(const long*)(Bb + n * (16 * 128) + cb);
      #pragma unroll
      for (int m = 0; m < 4; ++m) {
        long afrag = *(const long*)(Ab + m * (16 * 128) + cb);
        #pragma unroll
        for (int n = 0; n < 4; ++n)
          acc[m][n] = __builtin_amdgcn_mfma_f32_16x16x32_fp8_fp8(
              afrag, bfrag[n], acc[m][n], 0, 0, 0);
      }
    }
    // all LDS reads done in this wave, sync all waves -> safe to overwrite.
    asm volatile("s_waitcnt lgkmcnt(0)" ::: "memory");
    __builtin_amdgcn_sched_barrier(0);
    __builtin_amdgcn_s_barrier();
  }

  // ---- epilogue: unscale; exp(10*g); row + col sums; pair dots ----
  // smem reduction arrays aliased into As (all LDS reads drained above).
  float (*racc)[128] = (float (*)[128])As;        // [2][128]
  float (*cacc)[128] = ((float (*)[128])As) + 2;  // [2][128]

  float cs[4] = {0.f, 0.f, 0.f, 0.f};
  const int grow0 = brow + wr * 64;
  const int gcol0 = bcol + wc * 64;
  const float expc = TEMP_INV * DOT_UNSCALE;
  #pragma unroll
  for (int m = 0; m < 4; ++m) {
    #pragma unroll
    for (int j = 0; j < 4; ++j) {
      const int grow = grow0 + m * 16 + g * 4 + j;
      float v = 0.f;
      #pragma unroll
      for (int n = 0; n < 4; ++n) {
        const int gcol = gcol0 + n * 16 + r0;
        const float rawacc = acc[m][n][j];
        const float e = __expf(rawacc * expc);
        if (grow != gcol) { v += e; cs[n] += e; }   // skip self-similarity
        if (pair && (grow + NPER == gcol)) {        // positive-pair raw dot
          const float raw = rawacc * DOT_UNSCALE;
          s[grow] = raw;                            // dot(z_i, z_{i+NPER})
          s[gcol] = raw;                            // symmetric partner
        }
      }
      v += __shfl_xor(v, 1);
      v += __shfl_xor(v, 2);
      v += __shfl_xor(v, 4);
      v += __shfl_xor(v, 8);
      if (r0 == 0) racc[wc][wr * 64 + m * 16 + g * 4 + j] = v;
    }
  }
  #pragma unroll
  for (int n = 0; n < 4; ++n) {
    float v = cs[n];
    v += __shfl_xor(v, 16);
    v += __shfl_xor(v, 32);
    if (lane < 16) cacc[wr][wc * 64 + n * 16 + lane] = v;
  }
  __syncthreads();
  if (tid < 128) {
    atomicAdd(&rowsum[brow + tid], racc[0][tid] + racc[1][tid]);
  } else if (!diag) {
    const int i = tid - 128;
    atomicAdd(&rowsum[bcol + i], cacc[0][i] + cacc[1][i]);
  }
}

// ---------------------------------------------------------------------------
// Kernel 3: loss = mean_i( log(denom_i) - s_i/T ), 32 blocks + atomicAdd
// (out zeroed in k_normalize; stream order guarantees visibility).
// ---------------------------------------------------------------------------
__global__ __launch_bounds__(256) void k_loss(const float* __restrict__ rowsum,
                                              const float* __restrict__ s,
                                              float* __restrict__ out) {
  __shared__ float red[4];
  const int i = blockIdx.x * 256 + threadIdx.x;
  float v = logf(rowsum[i]) - s[i] * TEMP_INV;
  #pragma unroll
  for (int m = 1; m < 64; m <<= 1) v += __shfl_xor(v, m);
  const int w = threadIdx.x >> 6;
  if ((threadIdx.x & 63) == 0) red[w] = v;
  __syncthreads();
  if (threadIdx.x == 0)
    atomicAdd(out, (red[0] + red[1] + red[2] + red[3]) * (1.0f / (float)NROWS));
}

extern "C" void kernel_launch(void* const* d_in, const int* in_sizes, int n_in,
                              void* d_out, int out_size, void* d_ws, size_t ws_size,
                              hipStream_t stream) {
  const float* v0 = (const float*)d_in[0];
  const float* v1 = (const float*)d_in[1];
  float* out = (float*)d_out;

  unsigned char* z = (unsigned char*)d_ws;                      // 8192*512 B
  float* rowsum = (float*)((char*)d_ws + (size_t)NROWS * DIM);
  float* s      = rowsum + NROWS;

  k_normalize<<<NROWS / 4, 256, 0, stream>>>(v0, v1, z, rowsum, out);
  k_gemm_sym<<<NBLK, 256, 0, stream>>>(z, rowsum, s);
  k_loss<<<NROWS / 256, 256, 0, stream>>>(rowsum, s, out);
}

// Round 10
// 48.624 us; speedup vs baseline: 1.4804x; 1.0518x over previous
//
#include <hip/hip_runtime.h>
#include <hip/hip_bf16.h>
#include <cstdint>

#define NROWS 8192
#define NPER  4096
#define DIM   512
#define TEMP_INV 10.0f
#define FP8_SCALE 16.0f          // z scaled by 16 before e4m3 quantization
#define DOT_UNSCALE (1.0f / 256.0f)  // undo FP8_SCALE^2 on dot products
#define NB    64        // 8192 / 128 row-blocks
#define NBLK  2080      // NB*(NB+1)/2 upper-tri 128x128 tiles
#define PAIR_OFF 32     // NPER / 128

typedef float f32x4 __attribute__((ext_vector_type(4)));
typedef long  lx2   __attribute__((ext_vector_type(2)));   // 16 B = 2 fp8 frags

// ---------------------------------------------------------------------------
// Kernel 1: L2-normalize rows of [view0; view1] -> z (fp8 e4m3, [8192][512]),
// scaled by FP8_SCALE (moves typical |z|~0.04 out of the subnormal zone;
// e4m3 max 448 >> 16). Also zeroes rowsum and out.
// ---------------------------------------------------------------------------
__global__ __launch_bounds__(256) void k_normalize(const float* __restrict__ v0,
                                                   const float* __restrict__ v1,
                                                   unsigned char* __restrict__ z,
                                                   float* __restrict__ rowsum,
                                                   float* __restrict__ out) {
  if (blockIdx.x < 32) rowsum[blockIdx.x * 256 + threadIdx.x] = 0.f;
  if (blockIdx.x == 0 && threadIdx.x == 0) out[0] = 0.f;
  const int wid  = (blockIdx.x * 256 + threadIdx.x) >> 6;  // row
  const int lane = threadIdx.x & 63;
  if (wid >= NROWS) return;
  const float* src = (wid < NPER) ? (v0 + (size_t)wid * DIM)
                                  : (v1 + (size_t)(wid - NPER) * DIM);
  float4 a = *(const float4*)(src + lane * 8);
  float4 b = *(const float4*)(src + lane * 8 + 4);
  float ss = a.x*a.x + a.y*a.y + a.z*a.z + a.w*a.w
           + b.x*b.x + b.y*b.y + b.z*b.z + b.w*b.w;
  #pragma unroll
  for (int m = 1; m < 64; m <<= 1) ss += __shfl_xor(ss, m);
  float inv = FP8_SCALE / fmaxf(sqrtf(ss), 1e-12f);
  // pack 8 fp8 e4m3 (hardware v_cvt_pk_fp8_f32, RNE, OCP format on gfx950)
  int w0 = __builtin_amdgcn_cvt_pk_fp8_f32(a.x * inv, a.y * inv, 0, false);
  w0     = __builtin_amdgcn_cvt_pk_fp8_f32(a.z * inv, a.w * inv, w0, true);
  int w1 = __builtin_amdgcn_cvt_pk_fp8_f32(b.x * inv, b.y * inv, 0, false);
  w1     = __builtin_amdgcn_cvt_pk_fp8_f32(b.z * inv, b.w * inv, w1, true);
  uint2 p; p.x = (unsigned)w0; p.y = (unsigned)w1;
  *(uint2*)(z + (size_t)wid * DIM + lane * 8) = p;
}

// ---------------------------------------------------------------------------
// Kernel 2: symmetric fused G = z z^T in FP8 e4m3 (mfma_f32_16x16x32_fp8_fp8,
// bf16-rate, half the bytes). 128x128 upper-tri tiles, 4 waves (2x2),
// per-wave 64x64 (acc[4][4] = 64 AGPR), BK=128 SINGLE-buffered (32 KB LDS,
// 3 blocks/CU = the R4-verified residency optimum, 4 K-iterations).
// R10: conflict-free LDS reads. R9's per-kk ds_read_b64 pattern hit 4.26M
// bank-conflict cycles (~16% of GEMM time): lanes r0/r0+8 share the XOR key
// and both g-parities land on the same bank pair. Fix: read 16 B per lane
// (ds_read_b128) at phys 16B-slot (2g+p)^(r0&7) -- byte-identical bank
// pattern to the R4 bf16 kernel that measured 0 conflicts. Each b128 holds
// TWO 8-B MFMA fragments (halves). k-regrouping is a consistent relabeling
// applied identically to A and B, so the dot product is unchanged.
// Swizzle staging (rule #21) and R8 super-tile locality map kept.
// Positive-pair dots harvested from raw acc of tiles with bj-bi == 32.
// ---------------------------------------------------------------------------
__global__ __launch_bounds__(256, 3) void k_gemm_sym(const unsigned char* __restrict__ z,
                                                     float* __restrict__ rowsum,
                                                     float* __restrict__ s) {
  __shared__ __align__(16) unsigned char As[128 * 128];   // 16 KB
  __shared__ __align__(16) unsigned char Bs[128 * 128];   // 16 KB

  const int tid  = threadIdx.x;
  const int lane = tid & 63;
  const int w    = tid >> 6;      // 0..3
  const int wr   = w >> 1;        // 0..1 (row half)
  const int wc   = w & 1;         // 0..1 (col half)

  // T1 chunking: XCD x processes enumeration indices [x*260, (x+1)*260).
  const int orig = blockIdx.x;
  const int t = (orig & 7) * (NBLK / 8) + (orig >> 3);

  // ---- super-tile decode (R8) ----
  int a = 0;
  while (a < 7 && 484 * (a + 1) - 32 * (a + 1) * a <= t) ++a;
  int l = t - (484 * a - 32 * a * (a - 1));
  int ri, rj, sj;
  if (l < 36) {                      // diagonal super (si == sj == a)
    sj = a;
    ri = 0;
    while (l >= 8 - ri) { l -= 8 - ri; ++ri; }
    rj = ri + l;
  } else {                           // off-diagonal supers, 64 tiles each
    l -= 36;
    sj = a + 1 + (l >> 6);
    const int ll = l & 63;
    ri = ll >> 3; rj = ll & 7;
  }
  const int bi = a * 8 + ri;
  const int bj = sj * 8 + rj;
  const int brow = bi * 128;
  const int bcol = bj * 128;
  const bool diag = (bi == bj);
  const bool pair = (bj - bi == PAIR_OFF);  // contains positive-pair diagonal

  f32x4 acc[4][4];
  const f32x4 zero = {0.f, 0.f, 0.f, 0.f};
  #pragma unroll
  for (int m = 0; m < 4; ++m)
    #pragma unroll
    for (int n = 0; n < 4; ++n) acc[m][n] = zero;

  // stage one BK=128 K-slab (A and B tiles, 16 KB each). 8 global_load_lds
  // per thread (4 A + 4 B). Chunk = 8 rows x 128 B = 1 KB (one wave-load).
  // LDS dest linear; global source pre-swizzled: 16B-slot ^= (row & 7).
  const int srow = (lane >> 3);                  // 0..7 row within chunk
  const int skof = 16 * ((lane & 7) ^ srow);     // pre-swizzled k-offset (bytes)
  auto stage = [&](int k0) {
    #pragma unroll
    for (int i = 0; i < 4; ++i) {
      const int c = w * 4 + i;                   // chunk 0..15 (8 rows each)
      const int row_in = c * 8 + srow;
      const unsigned char* ga = z + (size_t)(brow + row_in) * DIM + k0 + skof;
      const unsigned char* gb = z + (size_t)(bcol + row_in) * DIM + k0 + skof;
      __builtin_amdgcn_global_load_lds(
          (const __attribute__((address_space(1))) void*)ga,
          (__attribute__((address_space(3))) void*)(&As[c * 1024]), 16, 0, 0);
      __builtin_amdgcn_global_load_lds(
          (const __attribute__((address_space(1))) void*)gb,
          (__attribute__((address_space(3))) void*)(&Bs[c * 1024]), 16, 0, 0);
    }
  };

  const int r0 = lane & 15;
  const int g  = lane >> 4;

  for (int kt = 0; kt < 4; ++kt) {
    stage(kt * 128);
    // single buffer: own loads drained, then all waves' loads visible.
    asm volatile("s_waitcnt vmcnt(0)" ::: "memory");
    __builtin_amdgcn_s_barrier();

    const char* Ab = (const char*)&As[0] + (size_t)(wr * 64 + r0) * 128;
    const char* Bb = (const char*)&Bs[0] + (size_t)(wc * 64 + r0) * 128;
    #pragma unroll
    for (int p = 0; p < 2; ++p) {
      // 16-B read at phys slot (2g+p)^(r0&7): R4-verified 0-conflict pattern.
      const int cb = (((2 * g + p) ^ (r0 & 7)) << 4);
      lx2 bfrag[4];
      #pragma unroll
      for (int n = 0; n < 4; ++n)
        bfrag[n] = *(const lx2*)(Bb + n * (16 * 128) + cb);
      #pragma unroll
      for (int m = 0; m < 4; ++m) {
        lx2 afrag = *(const lx2*)(Ab + m * (16 * 128) + cb);
        #pragma unroll
        for (int n = 0; n < 4; ++n) {
          acc[m][n] = __builtin_amdgcn_mfma_f32_16x16x32_fp8_fp8(
              afrag[0], bfrag[n][0], acc[m][n], 0, 0, 0);
          acc[m][n] = __builtin_amdgcn_mfma_f32_16x16x32_fp8_fp8(
              afrag[1], bfrag[n][1], acc[m][n], 0, 0, 0);
        }
      }
    }
    // all LDS reads done in this wave, sync all waves -> safe to overwrite.
    asm volatile("s_waitcnt lgkmcnt(0)" ::: "memory");
    __builtin_amdgcn_sched_barrier(0);
    __builtin_amdgcn_s_barrier();
  }

  // ---- epilogue: unscale; exp(10*g); row + col sums; pair dots ----
  // smem reduction arrays aliased into As (all LDS reads drained above).
  float (*racc)[128] = (float (*)[128])As;        // [2][128]
  float (*cacc)[128] = ((float (*)[128])As) + 2;  // [2][128]

  float cs[4] = {0.f, 0.f, 0.f, 0.f};
  const int grow0 = brow + wr * 64;
  const int gcol0 = bcol + wc * 64;
  const float expc = TEMP_INV * DOT_UNSCALE;
  #pragma unroll
  for (int m = 0; m < 4; ++m) {
    #pragma unroll
    for (int j = 0; j < 4; ++j) {
      const int grow = grow0 + m * 16 + g * 4 + j;
      float v = 0.f;
      #pragma unroll
      for (int n = 0; n < 4; ++n) {
        const int gcol = gcol0 + n * 16 + r0;
        const float rawacc = acc[m][n][j];
        const float e = __expf(rawacc * expc);
        if (grow != gcol) { v += e; cs[n] += e; }   // skip self-similarity
        if (pair && (grow + NPER == gcol)) {        // positive-pair raw dot
          const float raw = rawacc * DOT_UNSCALE;
          s[grow] = raw;                            // dot(z_i, z_{i+NPER})
          s[gcol] = raw;                            // symmetric partner
        }
      }
      v += __shfl_xor(v, 1);
      v += __shfl_xor(v, 2);
      v += __shfl_xor(v, 4);
      v += __shfl_xor(v, 8);
      if (r0 == 0) racc[wc][wr * 64 + m * 16 + g * 4 + j] = v;
    }
  }
  #pragma unroll
  for (int n = 0; n < 4; ++n) {
    float v = cs[n];
    v += __shfl_xor(v, 16);
    v += __shfl_xor(v, 32);
    if (lane < 16) cacc[wr][wc * 64 + n * 16 + lane] = v;
  }
  __syncthreads();
  if (tid < 128) {
    atomicAdd(&rowsum[brow + tid], racc[0][tid] + racc[1][tid]);
  } else if (!diag) {
    const int i = tid - 128;
    atomicAdd(&rowsum[bcol + i], cacc[0][i] + cacc[1][i]);
  }
}

// ---------------------------------------------------------------------------
// Kernel 3: loss = mean_i( log(denom_i) - s_i/T ), 32 blocks + atomicAdd
// (out zeroed in k_normalize; stream order guarantees visibility).
// ---------------------------------------------------------------------------
__global__ __launch_bounds__(256) void k_loss(const float* __restrict__ rowsum,
                                              const float* __restrict__ s,
                                              float* __restrict__ out) {
  __shared__ float red[4];
  const int i = blockIdx.x * 256 + threadIdx.x;
  float v = logf(rowsum[i]) - s[i] * TEMP_INV;
  #pragma unroll
  for (int m = 1; m < 64; m <<= 1) v += __shfl_xor(v, m);
  const int w = threadIdx.x >> 6;
  if ((threadIdx.x & 63) == 0) red[w] = v;
  __syncthreads();
  if (threadIdx.x == 0)
    atomicAdd(out, (red[0] + red[1] + red[2] + red[3]) * (1.0f / (float)NROWS));
}

extern "C" void kernel_launch(void* const* d_in, const int* in_sizes, int n_in,
                              void* d_out, int out_size, void* d_ws, size_t ws_size,
                              hipStream_t stream) {
  const float* v0 = (const float*)d_in[0];
  const float* v1 = (const float*)d_in[1];
  float* out = (float*)d_out;

  unsigned char* z = (unsigned char*)d_ws;                      // 8192*512 B
  float* rowsum = (float*)((char*)d_ws + (size_t)NROWS * DIM);
  float* s      = rowsum + NROWS;

  k_normalize<<<NROWS / 4, 256, 0, stream>>>(v0, v1, z, rowsum, out);
  k_gemm_sym<<<NBLK, 256, 0, stream>>>(z, rowsum, s);
  k_loss<<<NROWS / 256, 256, 0, stream>>>(rowsum, s, out);
}